// Round 8
// baseline (777.585 us; speedup 1.0000x reference)
//
#include <hip/hip_runtime.h>
#include <cstdint>
#include <cstddef>

#define DD 256    // full feature dim
#define DH 128    // half feature dim (dim-split pipeline)
#define SCAN_BLK 256
#define SCAN_ELEMS 2048  // 8 per thread

// ---------- helpers --------------------------------------------------------
__device__ __forceinline__ float4 f4mul(float4 a, float4 b) {
    return make_float4(a.x * b.x, a.y * b.y, a.z * b.z, a.w * b.w);
}
__device__ __forceinline__ float4 f4add(float4 a, float4 b) {
    return make_float4(a.x + b.x, a.y + b.y, a.z + b.z, a.w + b.w);
}
// 32-lane row loads: sl in [0,32), row is DH- or DD-wide
__device__ __forceinline__ float4 ldh4(const float* __restrict__ base, int row, int sl) {
    return ((const float4*)(base + (size_t)row * DH))[sl];
}
__device__ __forceinline__ float4 ldf4(const float* __restrict__ base, int row, int doff, int sl) {
    return ((const float4*)(base + (size_t)row * DD + doff))[sl];
}

// ================= fused CSR build (int atomics only) ======================
// cnt4[N3] | cnt3[N2] | cnt2[N1] zeroed by one memset before this
__global__ void k_count_all(const int* __restrict__ c2a, const int* __restrict__ c2b,
                            const int* __restrict__ c3a, const int* __restrict__ c3b,
                            const int* __restrict__ c4a, const int* __restrict__ c4b,
                            int n2, int n3, int n4,
                            int* __restrict__ cnt4, int* __restrict__ cnt3,
                            int* __restrict__ cnt2) {
    int e = blockIdx.x * blockDim.x + threadIdx.x;
    if (e < n4) { atomicAdd(&cnt4[c4a[e]], 1); atomicAdd(&cnt4[c4b[e]], 1); }
    if (e < n3) { atomicAdd(&cnt3[c3a[e]], 1); atomicAdd(&cnt3[c3b[e]], 1); }
    if (e < n2) { atomicAdd(&cnt2[c2a[e]], 1); atomicAdd(&cnt2[c2b[e]], 1); }
}

// CSR4 payload: OTHER endpoint's (c3a,c3b) pair; CSR3/CSR2: edge id
__global__ void k_fill_all(const int* __restrict__ c2a, const int* __restrict__ c2b,
                           const int* __restrict__ c3a, const int* __restrict__ c3b,
                           const int* __restrict__ c4a, const int* __restrict__ c4b,
                           int n2, int n3, int n4,
                           int* __restrict__ cur4, int* __restrict__ cur3,
                           int* __restrict__ cur2,
                           int2* __restrict__ entp, int* __restrict__ ent3,
                           int* __restrict__ ent2) {
    int e = blockIdx.x * blockDim.x + threadIdx.x;
    if (e < n4) {
        int a = c4a[e], b = c4b[e];
        int2 prA = make_int2(c3a[b], c3b[b]);
        int2 prB = make_int2(c3a[a], c3b[a]);
        int pa = atomicAdd(&cur4[a], 1);
        int pb = atomicAdd(&cur4[b], 1);
        entp[pa] = prA;
        entp[pb] = prB;
    }
    if (e < n3) {
        int a = c3a[e], b = c3b[e];
        int pa = atomicAdd(&cur3[a], 1);
        int pb = atomicAdd(&cur3[b], 1);
        ent3[pa] = e;
        ent3[pb] = e;
    }
    if (e < n2) {
        int a = c2a[e], b = c2b[e];
        int pa = atomicAdd(&cur2[a], 1);
        int pb = atomicAdd(&cur2[b], 1);
        ent2[pa] = e;
        ent2[pb] = e;
    }
}

__global__ void k_block_sums(const int* __restrict__ cnt, int n, int* __restrict__ bsum) {
    __shared__ int sdata[SCAN_BLK];
    int base = blockIdx.x * SCAN_ELEMS;
    int s = 0;
#pragma unroll
    for (int k = 0; k < 8; ++k) {
        int idx = base + threadIdx.x + k * SCAN_BLK;
        if (idx < n) s += cnt[idx];
    }
    sdata[threadIdx.x] = s;
    __syncthreads();
    for (int off = SCAN_BLK / 2; off > 0; off >>= 1) {
        if (threadIdx.x < off) sdata[threadIdx.x] += sdata[threadIdx.x + off];
        __syncthreads();
    }
    if (threadIdx.x == 0) bsum[blockIdx.x] = sdata[0];
}

__global__ void k_scan_bsums(int* __restrict__ bsum, int nb, int* __restrict__ total_out) {
    if (threadIdx.x == 0 && blockIdx.x == 0) {
        int acc = 0;
        for (int b = 0; b < nb; ++b) { int v = bsum[b]; bsum[b] = acc; acc += v; }
        *total_out = acc;
    }
}

// writes offs[idx] AND cursor[idx] (cursor = fill start positions)
__global__ void k_scan_final(const int* __restrict__ cnt, int n,
                             const int* __restrict__ bsum, int* __restrict__ offs,
                             int* __restrict__ cursor) {
    __shared__ int sdata[SCAN_BLK];
    int base = blockIdx.x * SCAN_ELEMS;
    int t0 = base + threadIdx.x * 8;
    int loc[8];
    int s = 0;
#pragma unroll
    for (int k = 0; k < 8; ++k) {
        int idx = t0 + k;
        int v = (idx < n) ? cnt[idx] : 0;
        loc[k] = s;
        s += v;
    }
    sdata[threadIdx.x] = s;
    __syncthreads();
    int run = s;
    for (int off = 1; off < SCAN_BLK; off <<= 1) {
        int add = (threadIdx.x >= (unsigned)off) ? sdata[threadIdx.x - off] : 0;
        __syncthreads();
        run += add;
        sdata[threadIdx.x] = run;
        __syncthreads();
    }
    int texcl = run - s + bsum[blockIdx.x];
#pragma unroll
    for (int k = 0; k < 8; ++k) {
        int idx = t0 + k;
        if (idx < n) {
            int v = texcl + loc[k];
            offs[idx] = v;
            cursor[idx] = v;
        }
    }
}

// ================= dim-split dense sweeps (2 rows/wave, 32-lane float4) ====
// h2h[q][0..127] = feat[c2a[q]][doff..] * feat[c2b[q]][doff..]
__global__ void k_h2_half(const float* __restrict__ feat, const int* __restrict__ c2a,
                          const int* __restrict__ c2b, float* __restrict__ h2h,
                          int n2, int doff) {
    int q = blockIdx.x * 8 + (threadIdx.x >> 5);
    int sl = threadIdx.x & 31;
    if (q >= n2) return;
    float4 v = f4mul(ldf4(feat, c2a[q], doff, sl), ldf4(feat, c2b[q], doff, sl));
    ((float4*)(h2h + (size_t)q * DH))[sl] = v;
}

// h3th[j-lo] = own * (1 + sum_e h2h[p.x]*h2h[p.y]); own = h2h[c3a[j]]*h2h[c3b[j]]
__global__ void k_h3tot_half(const float* __restrict__ h2h,
                             const int* __restrict__ c3a, const int* __restrict__ c3b,
                             const int* __restrict__ offs4, const int2* __restrict__ entp,
                             float* __restrict__ h3th, int lo, int hi) {
    int j = lo + blockIdx.x * 8 + (threadIdx.x >> 5);
    int sl = threadIdx.x & 31;
    if (j >= hi) return;
    float4 own = f4mul(ldh4(h2h, c3a[j], sl), ldh4(h2h, c3b[j], sl));
    float4 s = make_float4(0.f, 0.f, 0.f, 0.f);
    int e0 = offs4[j], e1 = offs4[j + 1];
    int e = e0;
    for (; e + 1 < e1; e += 2) {
        int2 p0 = entp[e], p1 = entp[e + 1];
        float4 a0 = ldh4(h2h, p0.x, sl), b0 = ldh4(h2h, p0.y, sl);
        float4 a1 = ldh4(h2h, p1.x, sl), b1 = ldh4(h2h, p1.y, sl);
        s = f4add(s, f4add(f4mul(a0, b0), f4mul(a1, b1)));
    }
    if (e < e1) {
        int2 p = entp[e];
        s = f4add(s, f4mul(ldh4(h2h, p.x, sl), ldh4(h2h, p.y, sl)));
    }
    float4 r = f4mul(own, make_float4(1.f + s.x, 1.f + s.y, 1.f + s.z, 1.f + s.w));
    ((float4*)(h3th + (size_t)(j - lo) * DH))[sl] = r;
}

// m2 mailbox: dst[q] = (first ? h2h[q] : dst[q]) + sum_{j in CSR3[q], j in [lo,hi)}
// primary path: dst == h2h (in place; wave touches only its own rows)
__global__ void k_m2_half(const float* __restrict__ h2h,
                          const int* __restrict__ offs3, const int* __restrict__ ent3,
                          const float* __restrict__ h3th, float* __restrict__ dst,
                          int n2, int lo, int hi, int first) {
    int q = blockIdx.x * 8 + (threadIdx.x >> 5);
    int sl = threadIdx.x & 31;
    if (q >= n2) return;
    float4 h = first ? ldh4(h2h, q, sl) : ldh4(dst, q, sl);
    int f0 = offs3[q], f1 = offs3[q + 1];
    int f = f0;
    for (; f + 1 < f1; f += 2) {
        int j0 = ent3[f], j1 = ent3[f + 1];
        bool in0 = (j0 >= lo) && (j0 < hi);
        bool in1 = (j1 >= lo) && (j1 < hi);
        if (in0 && in1) {
            h = f4add(h, f4add(ldh4(h3th, j0 - lo, sl), ldh4(h3th, j1 - lo, sl)));
        } else if (in0) {
            h = f4add(h, ldh4(h3th, j0 - lo, sl));
        } else if (in1) {
            h = f4add(h, ldh4(h3th, j1 - lo, sl));
        }
    }
    if (f < f1) {
        int j0 = ent3[f];
        if (j0 >= lo && j0 < hi) h = f4add(h, ldh4(h3th, j0 - lo, sl));
    }
    ((float4*)(dst + (size_t)q * DH))[sl] = h;
}

// out[i][doff..] = feat[i][doff..] + sum_{q in CSR2[i]} m2[q]
__global__ void k_h1_half(const float* __restrict__ feat, const float* __restrict__ m2,
                          const int* __restrict__ offs2, const int* __restrict__ ent2,
                          float* __restrict__ out, int n1, int doff) {
    int i = blockIdx.x * 8 + (threadIdx.x >> 5);
    int sl = threadIdx.x & 31;
    if (i >= n1) return;
    float4 h = ldf4(feat, i, doff, sl);
    int e0 = offs2[i], e1 = offs2[i + 1];
    int e = e0;
    for (; e + 1 < e1; e += 2) {
        int q0 = ent2[e], q1 = ent2[e + 1];
        h = f4add(h, f4add(ldh4(m2, q0, sl), ldh4(m2, q1, sl)));
    }
    if (e < e1) h = f4add(h, ldh4(m2, ent2[e], sl));
    ((float4*)(out + (size_t)i * DD + doff))[sl] = h;
}

// ================= GEMM + bias + SiLU, in-place on h [n1][256] =============
__device__ __forceinline__ float silu_f(float x) { return x / (1.0f + expf(-x)); }

__global__ __launch_bounds__(256) void k_gemm_silu(float* __restrict__ h,
                                                   const float* __restrict__ W,
                                                   const float* __restrict__ bias,
                                                   int n1) {
    __shared__ float As[32 * DD];  // 32 KB
    const int t = threadIdx.x;
    const int row0 = blockIdx.x * 32;

    const float4* hv = (const float4*)h;
    float4* As4 = (float4*)As;
#pragma unroll
    for (int i = 0; i < 8; ++i) {
        int idx = t + i * 256;
        int r = idx >> 6, c = idx & 63;
        int gr = row0 + r;
        float4 v = make_float4(0.f, 0.f, 0.f, 0.f);
        if (gr < n1) v = hv[(size_t)gr * 64 + c];
        As4[idx] = v;
    }
    __syncthreads();

    const int rg = t >> 6;
    const int cg = t & 63;
    const float4* Wv = (const float4*)W;

    float4 acc[8];
#pragma unroll
    for (int r = 0; r < 8; ++r) acc[r] = make_float4(0.f, 0.f, 0.f, 0.f);

    for (int k = 0; k < DD; k += 4) {
        float4 a[8];
#pragma unroll
        for (int r = 0; r < 8; ++r)
            a[r] = *(const float4*)&As[(rg * 8 + r) * DD + k];
#pragma unroll
        for (int kk = 0; kk < 4; ++kk) {
            float4 w = Wv[(size_t)(k + kk) * 64 + cg];
#pragma unroll
            for (int r = 0; r < 8; ++r) {
                float av = (kk == 0) ? a[r].x : (kk == 1) ? a[r].y
                         : (kk == 2) ? a[r].z : a[r].w;
                acc[r].x += av * w.x;
                acc[r].y += av * w.y;
                acc[r].z += av * w.z;
                acc[r].w += av * w.w;
            }
        }
    }

    float4 bb = ((const float4*)bias)[cg];
    float4* ho = (float4*)h;
#pragma unroll
    for (int r = 0; r < 8; ++r) {
        int gr = row0 + rg * 8 + r;
        if (gr >= n1) continue;
        float4 x = acc[r];
        x.x = silu_f(x.x + bb.x);
        x.y = silu_f(x.y + bb.y);
        x.z = silu_f(x.z + bb.z);
        x.w = silu_f(x.w + bb.w);
        ho[(size_t)gr * 64 + cg] = x;
    }
}

// ================= launcher ================================================
static inline size_t al16(size_t x) { return (x + 15) & ~(size_t)15; }

extern "C" void kernel_launch(void* const* d_in, const int* in_sizes, int n_in,
                              void* d_out, int out_size, void* d_ws, size_t ws_size,
                              hipStream_t stream) {
    const float* feat = (const float*)d_in[0];
    const int* c2a = (const int*)d_in[1];
    const int* c2b = (const int*)d_in[2];
    const int* c3a = (const int*)d_in[3];
    const int* c3b = (const int*)d_in[4];
    const int* c4a = (const int*)d_in[5];
    const int* c4b = (const int*)d_in[6];
    const float* W = (const float*)d_in[7];
    const float* bias = (const float*)d_in[8];

    const int N1 = in_sizes[0] / DD;
    const int N2 = in_sizes[1];
    const int N3 = in_sizes[3];
    const int N4 = in_sizes[5];
    float* out = (float*)d_out;
    char* ws = (char*)d_ws;

    dim3 blk(256);
    auto rows_grid8 = [](int n) { return dim3((unsigned)((n + 7) / 8)); };
    auto thr_grid = [](int n) { return dim3((unsigned)((n + 255) / 256)); };

    // ---- scratch layout ----
    size_t cnt4_b  = al16((size_t)N3 * 4);
    size_t cnt3_b  = al16((size_t)N2 * 4);
    size_t cnt2_b  = al16((size_t)N1 * 4);
    size_t cur4_b  = al16((size_t)N3 * 4);
    size_t cur3_b  = al16((size_t)N2 * 4);
    size_t cur2_b  = al16((size_t)N1 * 4);
    size_t bsum_b  = al16(4096);
    size_t offs4_b = al16((size_t)(N3 + 1) * 4);
    size_t entp_b  = al16((size_t)2 * N4 * 8);       // int2 per incidence
    size_t offs3_b = al16((size_t)(N2 + 1) * 4);
    size_t ent3_b  = al16((size_t)2 * N3 * 4);
    size_t offs2_b = al16((size_t)(N1 + 1) * 4);
    size_t ent2_b  = al16((size_t)2 * N2 * 4);
    size_t fixed_b = cnt4_b + cnt3_b + cnt2_b + cur4_b + cur3_b + cur2_b + bsum_b +
                     offs4_b + entp_b + offs3_b + ent3_b + offs2_b + ent2_b;
    size_t h2h_b = (size_t)N2 * DH * sizeof(float);        // 51.2 MB
    size_t h3th_full_b = (size_t)N3 * DH * sizeof(float);  // 102.4 MB

    char* p = ws;
    int* cnt4  = (int*)p; p += cnt4_b;   // cnt4|cnt3|cnt2 contiguous (one memset)
    int* cnt3  = (int*)p; p += cnt3_b;
    int* cnt2  = (int*)p; p += cnt2_b;
    int* cur4  = (int*)p; p += cur4_b;
    int* cur3  = (int*)p; p += cur3_b;
    int* cur2  = (int*)p; p += cur2_b;
    int* bsum  = (int*)p; p += bsum_b;
    int* offs4 = (int*)p; p += offs4_b;
    int2* entp = (int2*)p; p += entp_b;
    int* offs3 = (int*)p; p += offs3_b;
    int* ent3  = (int*)p; p += ent3_b;
    int* offs2 = (int*)p; p += offs2_b;
    int* ent2  = (int*)p; p += ent2_b;
    float* h2h = (float*)p; p += h2h_b;

    bool single = (ws_size >= fixed_b + h2h_b + h3th_full_b);

    auto scan_offs = [&](int* cn, int nnode, int* offs, int* cursor) {
        int nb = (nnode + SCAN_ELEMS - 1) / SCAN_ELEMS;
        k_block_sums<<<dim3((unsigned)nb), dim3(SCAN_BLK), 0, stream>>>(cn, nnode, bsum);
        k_scan_bsums<<<dim3(1), dim3(64), 0, stream>>>(bsum, nb, offs + nnode);
        k_scan_final<<<dim3((unsigned)nb), dim3(SCAN_BLK), 0, stream>>>(cn, nnode, bsum,
                                                                        offs, cursor);
    };

    // ---- fused CSR builds ----
    int maxE = N2 > N3 ? N2 : N3;
    if (N4 > maxE) maxE = N4;
    hipMemsetAsync(cnt4, 0, cnt4_b + cnt3_b + cnt2_b, stream);
    k_count_all<<<thr_grid(maxE), blk, 0, stream>>>(c2a, c2b, c3a, c3b, c4a, c4b,
                                                    N2, N3, N4, cnt4, cnt3, cnt2);
    scan_offs(cnt4, N3, offs4, cur4);
    scan_offs(cnt3, N2, offs3, cur3);
    scan_offs(cnt2, N1, offs2, cur2);
    k_fill_all<<<thr_grid(maxE), blk, 0, stream>>>(c2a, c2b, c3a, c3b, c4a, c4b,
                                                   N2, N3, N4, cur4, cur3, cur2,
                                                   entp, ent3, ent2);

    if (single) {
        float* h3th = (float*)p;
        for (int doff = 0; doff < DD; doff += DH) {
            k_h2_half<<<rows_grid8(N2), blk, 0, stream>>>(feat, c2a, c2b, h2h, N2, doff);
            k_h3tot_half<<<rows_grid8(N3), blk, 0, stream>>>(h2h, c3a, c3b, offs4, entp,
                                                             h3th, 0, N3);
            // m2 in place on h2h (all h3tot reads of h2h are complete)
            k_m2_half<<<rows_grid8(N2), blk, 0, stream>>>(h2h, offs3, ent3, h3th,
                                                          h2h, N2, 0, N3, 1);
            k_h1_half<<<rows_grid8(N1), blk, 0, stream>>>(feat, h2h, offs2, ent2,
                                                          out, N1, doff);
        }
    } else {
        // chunked fallback: separate m2h buffer; h3th chunks after it
        float* m2h = (float*)p;
        char* pc = p + h2h_b;
        float* h3th = (float*)pc;
        size_t free_b = (ws_size > fixed_b + 2 * h2h_b) ? ws_size - fixed_b - 2 * h2h_b : 0;
        int chunk_rows = (int)(free_b / ((size_t)DH * sizeof(float)));
        if (chunk_rows > N3) chunk_rows = N3;
        if (chunk_rows < 1) chunk_rows = 1;
        int C = (N3 + chunk_rows - 1) / chunk_rows;
        chunk_rows = (N3 + C - 1) / C;

        for (int doff = 0; doff < DD; doff += DH) {
            k_h2_half<<<rows_grid8(N2), blk, 0, stream>>>(feat, c2a, c2b, h2h, N2, doff);
            int first = 1;
            for (int lo = 0; lo < N3; lo += chunk_rows) {
                int hi = lo + chunk_rows;
                if (hi > N3) hi = N3;
                k_h3tot_half<<<rows_grid8(hi - lo), blk, 0, stream>>>(h2h, c3a, c3b,
                                                                      offs4, entp,
                                                                      h3th, lo, hi);
                k_m2_half<<<rows_grid8(N2), blk, 0, stream>>>(h2h, offs3, ent3, h3th,
                                                              m2h, N2, lo, hi, first);
                first = 0;
            }
            k_h1_half<<<rows_grid8(N1), blk, 0, stream>>>(feat, m2h, offs2, ent2,
                                                          out, N1, doff);
        }
    }

    // out = silu(out @ W + b), in-place
    k_gemm_silu<<<dim3((unsigned)((N1 + 31) / 32)), blk, 0, stream>>>(out, W, bias, N1);
}